// Round 2
// baseline (634.677 us; speedup 1.0000x reference)
//
#include <hip/hip_runtime.h>
#include <cstdint>
#include <cstddef>

// ---- problem constants (fixed by setup_inputs) ----
// B=8, N=4000, D_IN=D_QK=512, WINDOW=128, look=1/1, SCALE=64^-0.5
#define NB    8
#define NSEQ  4000
#define NPAD  4096
#define DIM   512
#define NWIN  32          // 4096/128
#define SCALE 0.125f      // 64^-0.5

typedef _Float16 half8 __attribute__((ext_vector_type(8)));
typedef _Float16 half4 __attribute__((ext_vector_type(4)));
typedef float    floatx4 __attribute__((ext_vector_type(4)));

#define NEG_MAX (-3.402823466e38f)

// ---------------------------------------------------------------------------
// K0: convert weights fp32 -> f16, folding SCALE into w_q.
// wh layout: [3][512][512] (n,k row-major). grid: 256 blocks x 256 thr x 4 elems
// ---------------------------------------------------------------------------
__global__ __launch_bounds__(256) void convert_w(
    const float* __restrict__ wq, const float* __restrict__ wk,
    const float* __restrict__ wv, _Float16* __restrict__ wh)
{
    int i = (blockIdx.x * 256 + threadIdx.x) * 4;
    floatx4 a = *(const floatx4*)(wq + i);
    half4 h;
    #pragma unroll
    for (int j = 0; j < 4; j++) h[j] = (_Float16)(a[j] * SCALE);
    *(half4*)(wh + i) = h;

    a = *(const floatx4*)(wk + i);
    #pragma unroll
    for (int j = 0; j < 4; j++) h[j] = (_Float16)a[j];
    *(half4*)(wh + 262144 + i) = h;

    a = *(const floatx4*)(wv + i);
    #pragma unroll
    for (int j = 0; j < 4; j++) h[j] = (_Float16)a[j];
    *(half4*)(wh + 524288 + i) = h;
}

// ---------------------------------------------------------------------------
// K1: QKV projection. out[m,n] = sum_k X[m,k] * W[n,k] + b[n]
// grid (250, 1, 3), block 512 (8 waves). Block: 128 rows x 512 cols (X read ONCE).
// Wave tile 64x128: wr = wid>>2 (2 row-groups), wc = wid&3 (4 col-groups).
// acc[4][8] = 128 VGPRs. Per k-step: 8 A-loads(fp32)+8 B-loads(f16) : 32 MFMA.
// z=0 -> qh [b][4096][512] f16 (W pre-scaled by SCALE, bias scaled here)
// z=1 -> kh [b][4096][512] f16
// z=2 -> vT [b][512][4096] f16 (transposed for PV B-fragments)
// Pad rows 4000..4095 are never written (poison is finite f16, masked downstream).
// ---------------------------------------------------------------------------
__global__ __launch_bounds__(512) void proj_kernel(
    const float* __restrict__ xq, const float* __restrict__ xk,
    const float* __restrict__ xv, const _Float16* __restrict__ wh,
    const float* __restrict__ bq, const float* __restrict__ bk,
    const float* __restrict__ bv,
    _Float16* __restrict__ qh, _Float16* __restrict__ kh,
    _Float16* __restrict__ vT)
{
    const int z  = blockIdx.z;
    const int m0 = blockIdx.x * 128;
    const int wid = threadIdx.x >> 6;
    const int wr = wid >> 2;          // 0..1  (row group, 64 rows)
    const int wc = wid & 3;           // 0..3  (col group, 128 cols)
    const int lane = threadIdx.x & 63;
    const int l16 = lane & 15, lg = lane >> 4;

    const float* X = (z == 0) ? xq : ((z == 1) ? xk : xv);
    const _Float16* W = wh + (size_t)z * 262144;
    const float* bias = (z == 0) ? bq : ((z == 1) ? bk : bv);

    const int rm = m0 + wr * 64;                        // wave's first row
    const float* xrow = X + (size_t)(rm + l16) * DIM + lg * 8;
    const _Float16* wb = W + (size_t)(wc * 128 + l16) * DIM + lg * 8;

    floatx4 acc[4][8];
    #pragma unroll
    for (int a = 0; a < 4; a++)
        #pragma unroll
        for (int t = 0; t < 8; t++) acc[a][t] = floatx4{0.f, 0.f, 0.f, 0.f};

    for (int ks = 0; ks < 16; ks++) {
        half8 af[4];
        #pragma unroll
        for (int a = 0; a < 4; a++) {
            floatx4 x0 = *(const floatx4*)(xrow + (size_t)a * 16 * DIM + ks * 32);
            floatx4 x1 = *(const floatx4*)(xrow + (size_t)a * 16 * DIM + ks * 32 + 4);
            #pragma unroll
            for (int j = 0; j < 4; j++) { af[a][j] = (_Float16)x0[j]; af[a][j + 4] = (_Float16)x1[j]; }
        }
        #pragma unroll
        for (int t = 0; t < 8; t++) {
            half8 bf = *(const half8*)(wb + (size_t)t * 16 * DIM + ks * 32);
            #pragma unroll
            for (int a = 0; a < 4; a++)
                acc[a][t] = __builtin_amdgcn_mfma_f32_16x16x32_f16(af[a], bf, acc[a][t], 0, 0, 0);
        }
    }

    const float bscale = (z == 0) ? SCALE : 1.0f;
    #pragma unroll
    for (int t = 0; t < 8; t++) {
        const int n = wc * 128 + t * 16 + l16;
        const float bn = bias[n] * bscale;
        #pragma unroll
        for (int a = 0; a < 4; a++) {
            if (z < 2) {
                _Float16* O = (z == 0) ? qh : kh;
                #pragma unroll
                for (int j = 0; j < 4; j++) {
                    int r = rm + a * 16 + lg * 4 + j;    // 0..31999
                    int bb = r / NSEQ;
                    int i  = r - bb * NSEQ;
                    O[((size_t)(bb * NPAD + i)) * DIM + n] = (_Float16)(acc[a][t][j] + bn);
                }
            } else {
                int r0 = rm + a * 16 + lg * 4;           // quad never splits a batch (4000%4==0)
                int bb = r0 / NSEQ;
                int i0 = r0 - bb * NSEQ;
                half4 pk;
                #pragma unroll
                for (int j = 0; j < 4; j++) pk[j] = (_Float16)(acc[a][t][j] + bn);
                *(half4*)(vT + ((size_t)(bb * DIM + n)) * NPAD + i0) = pk;
            }
        }
    }
}

// ---------------------------------------------------------------------------
// K2: S = Q_scaled . K^T  (128 x 384 per window), mask, softmax -> P (f16)
// grid (32, 8): x = window, y = batch. block 512 (8 waves), wave = 16 q-rows.
// All 8 waves share the same K B-fragments (L1 reuse). 24 acc tiles/wave.
// P layout: [b*32+w][128][384] f16.
// ---------------------------------------------------------------------------
__global__ __launch_bounds__(512) void attn_scores(
    const _Float16* __restrict__ qh, const _Float16* __restrict__ kh,
    const int* __restrict__ mask, _Float16* __restrict__ P)
{
    const int w = blockIdx.x;
    const int b = blockIdx.y;
    const int wv_ = threadIdx.x >> 6;                  // 0..7
    const int lane = threadIdx.x & 63;
    const int l16 = lane & 15, lg = lane >> 4;

    const int qr0 = w * 128 + wv_ * 16;                // padded row index, <= 4080
    const _Float16* qrow = qh + ((size_t)(b * NPAD + qr0 + l16)) * DIM + lg * 8;

    const int kbase = w * 128 - 128;
    int rowoff[24];
    #pragma unroll
    for (int t = 0; t < 24; t++) {
        int g = kbase + t * 16 + l16;
        int gc = g < 0 ? 0 : (g > NPAD - 1 ? NPAD - 1 : g);
        rowoff[t] = gc * DIM;
    }
    const _Float16* kbp = kh + (size_t)b * NPAD * DIM + lg * 8;

    floatx4 acc[24];
    #pragma unroll
    for (int t = 0; t < 24; t++) acc[t] = floatx4{0.f, 0.f, 0.f, 0.f};

    for (int ks = 0; ks < 16; ks++) {
        half8 a = *(const half8*)(qrow + ks * 32);
        #pragma unroll
        for (int t = 0; t < 24; t++) {
            half8 bf = *(const half8*)(kbp + rowoff[t] + ks * 32);
            acc[t] = __builtin_amdgcn_mfma_f32_16x16x32_f16(a, bf, acc[t], 0, 0, 0);
        }
    }

    // mask: keep iff key in [0,4000) and mask[b][g] != 0
    const int* mb = mask + b * NSEQ;
    #pragma unroll
    for (int t = 0; t < 24; t++) {
        int g = kbase + t * 16 + l16;
        bool keep = (g >= 0) && (g < NSEQ) && (mb[(g >= 0 && g < NSEQ) ? g : 0] != 0);
        if (!keep) acc[t] = floatx4{NEG_MAX, NEG_MAX, NEG_MAX, NEG_MAX};
    }

    _Float16* Pw = P + ((size_t)(b * NWIN + w)) * 128 * 384
                     + (size_t)(wv_ * 16) * 384;
    #pragma unroll
    for (int j = 0; j < 4; j++) {
        float mj = NEG_MAX;
        #pragma unroll
        for (int t = 0; t < 24; t++) mj = fmaxf(mj, acc[t][j]);
        mj = fmaxf(mj, __shfl_xor(mj, 1));
        mj = fmaxf(mj, __shfl_xor(mj, 2));
        mj = fmaxf(mj, __shfl_xor(mj, 4));
        mj = fmaxf(mj, __shfl_xor(mj, 8));

        float p[24];
        float lsum = 0.f;
        #pragma unroll
        for (int t = 0; t < 24; t++) { p[t] = __expf(acc[t][j] - mj); lsum += p[t]; }
        lsum += __shfl_xor(lsum, 1);
        lsum += __shfl_xor(lsum, 2);
        lsum += __shfl_xor(lsum, 4);
        lsum += __shfl_xor(lsum, 8);
        float rinv = 1.0f / lsum;

        int r = lg * 4 + j;
        #pragma unroll
        for (int t = 0; t < 24; t++)
            Pw[(size_t)r * 384 + t * 16 + l16] = (_Float16)(p[t] * rinv);
    }
}

// ---------------------------------------------------------------------------
// K3: O = P . V  (128 x 512 per window), write fp32 output rows < 4000.
// grid (4, 32, 8): x = d-quarter, y = window, z = batch. block 512 (8 waves).
// Clamped V-row reads always multiply P == 0 (masked columns).
// ---------------------------------------------------------------------------
__global__ __launch_bounds__(512) void attn_pv(
    const _Float16* __restrict__ P, const _Float16* __restrict__ vT,
    float* __restrict__ out)
{
    const int dq = blockIdx.x;
    const int w  = blockIdx.y;
    const int b  = blockIdx.z;
    const int wv_ = threadIdx.x >> 6;
    const int lane = threadIdx.x & 63;
    const int l16 = lane & 15, lg = lane >> 4;
    const int d0 = dq * 128;

    const _Float16* Pw = P + ((size_t)(b * NWIN + w)) * 128 * 384
                           + (size_t)(wv_ * 16 + l16) * 384 + lg * 8;
    const _Float16* vb = vT + (size_t)b * DIM * NPAD;

    floatx4 acc[8];
    #pragma unroll
    for (int t = 0; t < 8; t++) acc[t] = floatx4{0.f, 0.f, 0.f, 0.f};

    for (int ks = 0; ks < 12; ks++) {
        half8 a = *(const half8*)(Pw + ks * 32);
        int i0 = w * 128 - 128 + ks * 32 + lg * 8;     // multiple of 8
        i0 = i0 < 0 ? 0 : (i0 > NPAD - 8 ? NPAD - 8 : i0);   // clamped rows have P==0
        #pragma unroll
        for (int t = 0; t < 8; t++) {
            const int d = d0 + t * 16 + l16;
            half8 bf = *(const half8*)(vb + (size_t)d * NPAD + i0);
            acc[t] = __builtin_amdgcn_mfma_f32_16x16x32_f16(a, bf, acc[t], 0, 0, 0);
        }
    }

    const int rl = wv_ * 16 + lg * 4;
    #pragma unroll
    for (int j = 0; j < 4; j++) {
        int i = w * 128 + rl + j;
        if (i < NSEQ) {
            float* orow = out + ((size_t)(b * NSEQ + i)) * DIM;
            #pragma unroll
            for (int t = 0; t < 8; t++) orow[d0 + t * 16 + l16] = acc[t][j];
        }
    }
}

// ---------------------------------------------------------------------------
extern "C" void kernel_launch(void* const* d_in, const int* in_sizes, int n_in,
                              void* d_out, int out_size, void* d_ws, size_t ws_size,
                              hipStream_t stream)
{
    const float* xq = (const float*)d_in[0];
    const float* xk = (const float*)d_in[1];
    const float* xv = (const float*)d_in[2];
    const int*  msk = (const int*)d_in[3];
    const float* wq = (const float*)d_in[4];
    const float* bq = (const float*)d_in[5];
    const float* wk = (const float*)d_in[6];
    const float* bk = (const float*)d_in[7];
    const float* wv = (const float*)d_in[8];
    const float* bv = (const float*)d_in[9];

    _Float16* qh = (_Float16*)d_ws;                       // [8][4096][512]
    _Float16* kh = qh + (size_t)NB * NPAD * DIM;          // [8][4096][512]
    _Float16* vT = kh + (size_t)NB * NPAD * DIM;          // [8][512][4096]
    _Float16* wh = vT + (size_t)NB * NPAD * DIM;          // [3][512][512]
    _Float16* P  = wh + (size_t)3 * DIM * DIM;            // [256][128][384]
    float* out = (float*)d_out;

    convert_w<<<dim3(256), dim3(256), 0, stream>>>(wq, wk, wv, wh);
    proj_kernel<<<dim3(250, 1, 3), dim3(512), 0, stream>>>(
        xq, xk, xv, wh, bq, bk, bv, qh, kh, vT);
    attn_scores<<<dim3(NWIN, NB), dim3(512), 0, stream>>>(qh, kh, msk, P);
    attn_pv<<<dim3(4, NWIN, NB), dim3(512), 0, stream>>>(P, vT, out);
}

// Round 4
// 469.818 us; speedup vs baseline: 1.3509x; 1.3509x over previous
//
#include <hip/hip_runtime.h>
#include <cstdint>
#include <cstddef>

// ---- problem constants (fixed by setup_inputs) ----
// B=8, N=4000, D_IN=D_QK=512, WINDOW=128, look=1/1, SCALE=64^-0.5
#define NB    8
#define NSEQ  4000
#define NPAD  4096
#define DIM   512
#define NWIN  32          // 4096/128
#define SCALE 0.125f      // 64^-0.5
#define NEG_MAX (-3.402823466e38f)

typedef _Float16 half8 __attribute__((ext_vector_type(8)));
typedef _Float16 half4 __attribute__((ext_vector_type(4)));
typedef float    floatx4 __attribute__((ext_vector_type(4)));

typedef const __attribute__((address_space(1))) void* gas_p;
typedef __attribute__((address_space(3))) void*       las_p;

// async global->LDS, 16B per lane. LDS dest is wave-uniform base + lane*16.
__device__ __forceinline__ void gl_lds16(const void* g, void* l) {
    __builtin_amdgcn_global_load_lds((gas_p)g, (las_p)l, 16, 0, 0);
}

// ---------------------------------------------------------------------------
// K0: weights fp32 -> f16, folding SCALE into w_q. wh: [3][512][512] (n,k).
// ---------------------------------------------------------------------------
__global__ __launch_bounds__(256) void convert_w(
    const float* __restrict__ wq, const float* __restrict__ wk,
    const float* __restrict__ wv, _Float16* __restrict__ wh)
{
    int i = (blockIdx.x * 256 + threadIdx.x) * 4;
    floatx4 a = *(const floatx4*)(wq + i);
    half4 h;
    #pragma unroll
    for (int j = 0; j < 4; j++) h[j] = (_Float16)(a[j] * SCALE);
    *(half4*)(wh + i) = h;

    a = *(const floatx4*)(wk + i);
    #pragma unroll
    for (int j = 0; j < 4; j++) h[j] = (_Float16)a[j];
    *(half4*)(wh + 262144 + i) = h;

    a = *(const floatx4*)(wv + i);
    #pragma unroll
    for (int j = 0; j < 4; j++) h[j] = (_Float16)a[j];
    *(half4*)(wh + 524288 + i) = h;
}

// ---------------------------------------------------------------------------
// K1: fused projection GEMM, all 3 z in one launch. C = cvt16(X_fp32)*W^T + b.
// grid (250,4,3), block 256 (4 waves 2x2; wave tile 64x64, acc[4][4]).
// A: reg-staged fp32->f16 (load early, cvt+ds_write late — T14 split).
// B: f16 weights via global_load_lds dwordx4. LDS dbuf [k8][row][8], BK=32.
// z=0 -> qh [b][4096][512] (W pre-scaled by SCALE), z=1 -> kh,
// z=2 -> vT [b][512][4096] (transposed for PV B-fragments).
// Pad rows 4000..4095 never written (poison finite f16, masked downstream).
// ---------------------------------------------------------------------------
__global__ __launch_bounds__(256) void proj_gemm(
    const float* __restrict__ xq, const float* __restrict__ xk,
    const float* __restrict__ xv, const _Float16* __restrict__ wh,
    const float* __restrict__ bq, const float* __restrict__ bk,
    const float* __restrict__ bv,
    _Float16* __restrict__ qh, _Float16* __restrict__ kh,
    _Float16* __restrict__ vT)
{
    const int z  = blockIdx.z;
    const int m0 = blockIdx.x * 128;
    const int n0 = blockIdx.y * 128;
    const int tid = threadIdx.x;
    const int wid = tid >> 6, lane = tid & 63;
    const int l16 = lane & 15, lg = lane >> 4;
    const int wr = wid >> 1, wc = wid & 1;

    __shared__ __align__(16) _Float16 AB[2][2][4096];   // [buf][A/B][k8*1024+row*8] = 32 KB

    const float* X = (z == 0) ? xq : ((z == 1) ? xk : xv);
    const _Float16* Wz = wh + (size_t)z * DIM * DIM;

    // byte offsets within an 8 KB half-buffer: s = k8*2048 + row*16
    const int s0 = tid * 16;
    const int s1 = 4096 + tid * 16;
    const int k8_0 = s0 >> 11, row_0 = (s0 >> 4) & 127;
    const int k8_1 = s1 >> 11, row_1 = (s1 >> 4) & 127;
    const int ldsu0 = wid * 1024;          // wave-uniform chunk bases (bytes)
    const int ldsu1 = 4096 + wid * 1024;

    const float* xp0 = X + (size_t)(m0 + row_0) * DIM + k8_0 * 8;
    const float* xp1 = X + (size_t)(m0 + row_1) * DIM + k8_1 * 8;

    floatx4 acc[4][4];
    #pragma unroll
    for (int m = 0; m < 4; m++)
        #pragma unroll
        for (int n = 0; n < 4; n++) acc[m][n] = floatx4{0.f, 0.f, 0.f, 0.f};

    // ---- prologue: stage tile 0 into buf 0 ----
    {
        floatx4 a0 = *(const floatx4*)(xp0);
        floatx4 a1 = *(const floatx4*)(xp0 + 4);
        floatx4 a2 = *(const floatx4*)(xp1);
        floatx4 a3 = *(const floatx4*)(xp1 + 4);
        gl_lds16(Wz + (size_t)(n0 + row_0) * DIM + k8_0 * 8, (char*)&AB[0][1][0] + ldsu0);
        gl_lds16(Wz + (size_t)(n0 + row_1) * DIM + k8_1 * 8, (char*)&AB[0][1][0] + ldsu1);
        half8 h0, h1;
        #pragma unroll
        for (int j = 0; j < 4; j++) {
            h0[j] = (_Float16)a0[j]; h0[j + 4] = (_Float16)a1[j];
            h1[j] = (_Float16)a2[j]; h1[j + 4] = (_Float16)a3[j];
        }
        *(half8*)((char*)&AB[0][0][0] + s0) = h0;
        *(half8*)((char*)&AB[0][0][0] + s1) = h1;
    }
    __syncthreads();

    for (int ks = 0; ks < 16; ks++) {
        const int cur = ks & 1;
        floatx4 a0, a1, a2, a3;
        if (ks < 15) {
            const int k0 = (ks + 1) * 32;
            a0 = *(const floatx4*)(xp0 + k0);          // issue early (hide HBM)
            a1 = *(const floatx4*)(xp0 + k0 + 4);
            a2 = *(const floatx4*)(xp1 + k0);
            a3 = *(const floatx4*)(xp1 + k0 + 4);
            gl_lds16(Wz + (size_t)(n0 + row_0) * DIM + k0 + k8_0 * 8,
                     (char*)&AB[cur ^ 1][1][0] + ldsu0);
            gl_lds16(Wz + (size_t)(n0 + row_1) * DIM + k0 + k8_1 * 8,
                     (char*)&AB[cur ^ 1][1][0] + ldsu1);
        }
        const _Float16* Ar = &AB[cur][0][lg * 1024 + (wr * 64 + l16) * 8];
        const _Float16* Br = &AB[cur][1][lg * 1024 + (wc * 64 + l16) * 8];
        half8 af[4], bf[4];
        #pragma unroll
        for (int m = 0; m < 4; m++) af[m] = *(const half8*)(Ar + m * 128);
        #pragma unroll
        for (int n = 0; n < 4; n++) bf[n] = *(const half8*)(Br + n * 128);
        #pragma unroll
        for (int m = 0; m < 4; m++)
            #pragma unroll
            for (int n = 0; n < 4; n++)
                acc[m][n] = __builtin_amdgcn_mfma_f32_16x16x32_f16(af[m], bf[n], acc[m][n], 0, 0, 0);
        if (ks < 15) {
            half8 h0, h1;                              // cvt + write late
            #pragma unroll
            for (int j = 0; j < 4; j++) {
                h0[j] = (_Float16)a0[j]; h0[j + 4] = (_Float16)a1[j];
                h1[j] = (_Float16)a2[j]; h1[j + 4] = (_Float16)a3[j];
            }
            *(half8*)((char*)&AB[cur ^ 1][0][0] + s0) = h0;
            *(half8*)((char*)&AB[cur ^ 1][0][0] + s1) = h1;
            __syncthreads();
        }
    }

    const float* bias = (z == 0) ? bq : ((z == 1) ? bk : bv);
    const float bscale = (z == 0) ? SCALE : 1.0f;
    #pragma unroll
    for (int n = 0; n < 4; n++) {
        const int ncol = n0 + wc * 64 + n * 16 + l16;
        const float bn = bias[ncol] * bscale;
        #pragma unroll
        for (int m = 0; m < 4; m++) {
            const int r0 = m0 + wr * 64 + m * 16 + lg * 4;  // quad never splits batch
            const int bb = r0 / NSEQ;
            const int i0 = r0 - bb * NSEQ;
            if (z < 2) {
                _Float16* O = (z == 0) ? qh : kh;
                #pragma unroll
                for (int j = 0; j < 4; j++)
                    O[((size_t)(bb * NPAD + i0 + j)) * DIM + ncol] = (_Float16)(acc[m][n][j] + bn);
            } else {
                half4 pk;
                #pragma unroll
                for (int j = 0; j < 4; j++) pk[j] = (_Float16)(acc[m][n][j] + bn);
                *(half4*)(vT + ((size_t)(bb * DIM + ncol)) * NPAD + i0) = pk;
            }
        }
    }
}

// ---------------------------------------------------------------------------
// K2: S = Q_scaled . K^T (128x384/window), mask, softmax -> P (f16).
// grid (2,32,8): x = row-half, y = window, z = batch. block 256 (4 waves;
// wave = 16 q-rows x 384 keys, acc[24]). 2 blocks/window -> 2-3 blocks/CU
// co-resident (barrier overlap). K staged in LDS [k8][key][8] dbuf (48 KB)
// via global_load_lds; Q register operand, 1-step prefetch.
// P: [b*32+w][128][384].
// ---------------------------------------------------------------------------
__global__ __launch_bounds__(256) void attn_scores(
    const _Float16* __restrict__ qh, const _Float16* __restrict__ kh,
    const int* __restrict__ mask, _Float16* __restrict__ P)
{
    const int h = blockIdx.x, w = blockIdx.y, b = blockIdx.z;
    const int tid = threadIdx.x;
    const int wid = tid >> 6, lane = tid & 63;
    const int l16 = lane & 15, lg = lane >> 4;

    __shared__ __align__(16) _Float16 Kl[2][12288];   // [k8*3072 + key*8], 24 KB/buf

    const int kbase = w * 128 - 128;
    const _Float16* khb = kh + (size_t)b * NPAD * DIM;

    // 6 chunks of 4 KB: s = c*4096 + tid*16; k8 = s/6144; key = (s%6144)>>4
    int srcoff[6], ldsoff[6];
    #pragma unroll
    for (int c = 0; c < 6; c++) {
        int s = c * 4096 + tid * 16;
        int k8 = s / 6144;
        int key = (s - k8 * 6144) >> 4;
        int g = kbase + key;
        int gc = g < 0 ? 0 : (g > NPAD - 1 ? NPAD - 1 : g);
        srcoff[c] = gc * DIM + k8 * 8;
        ldsoff[c] = c * 4096 + wid * 1024;
    }

#define STAGE_K2(bb, k0) do {                                                   \
    _Pragma("unroll")                                                           \
    for (int c = 0; c < 6; c++)                                                 \
        gl_lds16(khb + (size_t)srcoff[c] + (k0), (char*)&Kl[bb][0] + ldsoff[c]);\
} while (0)

    const int qr0 = w * 128 + h * 64 + wid * 16;       // <= 4080
    const _Float16* qrow = qh + ((size_t)(b * NPAD + qr0 + l16)) * DIM + lg * 8;

    floatx4 acc[24];
    #pragma unroll
    for (int t = 0; t < 24; t++) acc[t] = floatx4{0.f, 0.f, 0.f, 0.f};

    half8 qcur = *(const half8*)(qrow);
    STAGE_K2(0, 0);
    __syncthreads();
    for (int ks = 0; ks < 16; ks++) {
        const int cur = ks & 1;
        half8 qnext;
        if (ks < 15) {
            STAGE_K2(cur ^ 1, (ks + 1) * 32);
            qnext = *(const half8*)(qrow + (ks + 1) * 32);
        }
        const _Float16* Kb = &Kl[cur][lg * 3072 + l16 * 8];
        #pragma unroll
        for (int t = 0; t < 24; t++) {
            half8 bf = *(const half8*)(Kb + t * 128);
            acc[t] = __builtin_amdgcn_mfma_f32_16x16x32_f16(qcur, bf, acc[t], 0, 0, 0);
        }
        if (ks < 15) { __syncthreads(); qcur = qnext; }
    }
#undef STAGE_K2

    // mask: keep iff key in [0,4000) and mask[b][g] != 0
    const int* mb = mask + b * NSEQ;
    #pragma unroll
    for (int t = 0; t < 24; t++) {
        int g = kbase + t * 16 + l16;
        bool keep = (g >= 0) && (g < NSEQ) && (mb[(g >= 0 && g < NSEQ) ? g : 0] != 0);
        if (!keep) acc[t] = floatx4{NEG_MAX, NEG_MAX, NEG_MAX, NEG_MAX};
    }

    _Float16* Pw = P + ((size_t)(b * NWIN + w)) * 128 * 384
                     + (size_t)(h * 64 + wid * 16) * 384;
    #pragma unroll
    for (int j = 0; j < 4; j++) {
        float mj = NEG_MAX;
        #pragma unroll
        for (int t = 0; t < 24; t++) mj = fmaxf(mj, acc[t][j]);
        mj = fmaxf(mj, __shfl_xor(mj, 1));
        mj = fmaxf(mj, __shfl_xor(mj, 2));
        mj = fmaxf(mj, __shfl_xor(mj, 4));
        mj = fmaxf(mj, __shfl_xor(mj, 8));

        float p[24];
        float lsum = 0.f;
        #pragma unroll
        for (int t = 0; t < 24; t++) { p[t] = __expf(acc[t][j] - mj); lsum += p[t]; }
        lsum += __shfl_xor(lsum, 1);
        lsum += __shfl_xor(lsum, 2);
        lsum += __shfl_xor(lsum, 4);
        lsum += __shfl_xor(lsum, 8);
        float rinv = 1.0f / lsum;

        int r = lg * 4 + j;
        #pragma unroll
        for (int t = 0; t < 24; t++)
            Pw[(size_t)r * 384 + t * 16 + l16] = (_Float16)(p[t] * rinv);
    }
}

// ---------------------------------------------------------------------------
// K3: O = P . V (128 q x 128 d per block). grid (4,32,8), block 256 (4 waves;
// wave = 32q x 128d, acc[2][8]). P and V staged in LDS dbuf (32 KB).
// Clamped V-row reads always multiply P == 0 (masked columns).
// ---------------------------------------------------------------------------
__global__ __launch_bounds__(256) void attn_pv(
    const _Float16* __restrict__ P, const _Float16* __restrict__ vT,
    float* __restrict__ out)
{
    const int dq = blockIdx.x, w = blockIdx.y, b = blockIdx.z;
    const int tid = threadIdx.x;
    const int wid = tid >> 6, lane = tid & 63;
    const int l16 = lane & 15, lg = lane >> 4;
    const int d0 = dq * 128;

    __shared__ __align__(16) _Float16 Pl[2][4096];   // [i8*1024 + q*8]
    __shared__ __align__(16) _Float16 Vl[2][4096];   // [i8*1024 + d*8]

    const _Float16* Pw = P + ((size_t)(b * NWIN + w)) * 128 * 384;
    const _Float16* vb = vT + (size_t)b * DIM * NPAD;
    const int iw_base = w * 128 - 128;

    const int s0 = tid * 16;
    const int s1 = 4096 + tid * 16;
    const int k8_0 = s0 >> 11, row_0 = (s0 >> 4) & 127;
    const int k8_1 = s1 >> 11, row_1 = (s1 >> 4) & 127;
    const int ldsu0 = wid * 1024;
    const int ldsu1 = 4096 + wid * 1024;

#define STAGE_K3(bb, ks) do {                                                   \
    int i0 = (ks) * 32;                                                         \
    gl_lds16(Pw + (size_t)row_0 * 384 + i0 + k8_0 * 8, (char*)&Pl[bb][0] + ldsu0);\
    gl_lds16(Pw + (size_t)row_1 * 384 + i0 + k8_1 * 8, (char*)&Pl[bb][0] + ldsu1);\
    int ig0 = iw_base + i0 + k8_0 * 8;                                          \
    ig0 = ig0 < 0 ? 0 : (ig0 > NPAD - 8 ? NPAD - 8 : ig0);                      \
    int ig1 = iw_base + i0 + k8_1 * 8;                                          \
    ig1 = ig1 < 0 ? 0 : (ig1 > NPAD - 8 ? NPAD - 8 : ig1);                      \
    gl_lds16(vb + (size_t)(d0 + row_0) * NPAD + ig0, (char*)&Vl[bb][0] + ldsu0);\
    gl_lds16(vb + (size_t)(d0 + row_1) * NPAD + ig1, (char*)&Vl[bb][0] + ldsu1);\
} while (0)

    floatx4 acc[2][8];
    #pragma unroll
    for (int m = 0; m < 2; m++)
        #pragma unroll
        for (int n = 0; n < 8; n++) acc[m][n] = floatx4{0.f, 0.f, 0.f, 0.f};

    STAGE_K3(0, 0);
    __syncthreads();
    for (int ks = 0; ks < 12; ks++) {
        const int cur = ks & 1;
        if (ks < 11) STAGE_K3(cur ^ 1, ks + 1);
        const _Float16* Pr = &Pl[cur][lg * 1024 + (wid * 32 + l16) * 8];
        const _Float16* Vr = &Vl[cur][lg * 1024 + l16 * 8];
        half8 pa[2], vf[8];
        #pragma unroll
        for (int m = 0; m < 2; m++) pa[m] = *(const half8*)(Pr + m * 128);
        #pragma unroll
        for (int n = 0; n < 8; n++) vf[n] = *(const half8*)(Vr + n * 128);
        #pragma unroll
        for (int m = 0; m < 2; m++)
            #pragma unroll
            for (int n = 0; n < 8; n++)
                acc[m][n] = __builtin_amdgcn_mfma_f32_16x16x32_f16(pa[m], vf[n], acc[m][n], 0, 0, 0);
        if (ks < 11) __syncthreads();
    }
#undef STAGE_K3

    #pragma unroll
    for (int m = 0; m < 2; m++) {
        #pragma unroll
        for (int j = 0; j < 4; j++) {
            int i = w * 128 + wid * 32 + m * 16 + lg * 4 + j;
            if (i < NSEQ) {
                float* orow = out + ((size_t)b * NSEQ + i) * DIM + d0;
                #pragma unroll
                for (int n = 0; n < 8; n++) orow[n * 16 + l16] = acc[m][n][j];
            }
        }
    }
}

// ---------------------------------------------------------------------------
extern "C" void kernel_launch(void* const* d_in, const int* in_sizes, int n_in,
                              void* d_out, int out_size, void* d_ws, size_t ws_size,
                              hipStream_t stream)
{
    const float* xq = (const float*)d_in[0];
    const float* xk = (const float*)d_in[1];
    const float* xv = (const float*)d_in[2];
    const int*  msk = (const int*)d_in[3];
    const float* wq = (const float*)d_in[4];
    const float* bq = (const float*)d_in[5];
    const float* wk = (const float*)d_in[6];
    const float* bk = (const float*)d_in[7];
    const float* wv = (const float*)d_in[8];
    const float* bv = (const float*)d_in[9];

    // ws (halves): qh/kh/vT 16,777,216 each | wh 786,432 | P 12,582,912
    // total ~127.4 MB == round-2's proven footprint.
    _Float16* qh = (_Float16*)d_ws;                       // [8][4096][512]
    _Float16* kh = qh + (size_t)NB * NPAD * DIM;          // [8][4096][512]
    _Float16* vT = kh + (size_t)NB * NPAD * DIM;          // [8][512][4096]
    _Float16* wh = vT + (size_t)NB * NPAD * DIM;          // [3][512][512]
    _Float16* P  = wh + (size_t)3 * DIM * DIM;            // [256][128][384]
    float* out = (float*)d_out;

    convert_w<<<dim3(256), dim3(256), 0, stream>>>(wq, wk, wv, wh);
    proj_gemm<<<dim3(250, 4, 3), dim3(256), 0, stream>>>(
        xq, xk, xv, wh, bq, bk, bv, qh, kh, vT);
    attn_scores<<<dim3(2, NWIN, NB), dim3(256), 0, stream>>>(qh, kh, msk, P);
    attn_pv<<<dim3(4, NWIN, NB), dim3(256), 0, stream>>>(P, vT, out);
}